// Round 7
// baseline (113.227 us; speedup 1.0000x reference)
//
#include <hip/hip_runtime.h>
#include <hip/hip_bf16.h>
#include <math.h>

#define MC_    10
#define IN_C_  16
#define OUT_C_ 32
#define K_     3
#define D_     144
#define KP_    160                 // K padded to 5 x 32
#define H_     128
#define W_     128
#define HW_    64
#define B_     8
#define PSTR_  68                  // Phase LDS stride (floats): 16B-aligned, bank-skewed

typedef __attribute__((ext_vector_type(8))) short short8;   // 8 bf16 = 4 VGPR
typedef __attribute__((ext_vector_type(4))) float f32x4;

static __device__ __forceinline__ unsigned short f2bf(float v) {
    union { float f; unsigned u; } x; x.f = v;
    unsigned r = x.u + 0x7fff + ((x.u >> 16) & 1);           // RNE
    return (unsigned short)(r >> 16);
}

// ---------------------------------------------------------------------------
// Kernel 1: reparameterize + transpose + bf16-cast weights into d_ws:
//   W2[mc][oc][k] (k padded to 160, zeros for k>=144), k = (kh*3+kw)*16+ic
// ---------------------------------------------------------------------------
__global__ __launch_bounds__(256) void prep_w_kernel(
    const float* __restrict__ eps, const float* __restrict__ logsig,
    const float* __restrict__ mean, unsigned short* __restrict__ w2)
{
    int i = blockIdx.x * 256 + threadIdx.x;      // over 10*32*160 = 51200
    if (i >= MC_ * OUT_C_ * KP_) return;
    int k  = i % KP_;
    int oc = (i / KP_) % OUT_C_;
    int mc = i / (KP_ * OUT_C_);
    float val = 0.0f;
    if (k < D_) {
        int doc = k * OUT_C_ + oc;
        val = eps[mc * (D_ * OUT_C_) + doc] * __expf(0.5f * logsig[doc]) + mean[doc];
    }
    w2[i] = f2bf(val);
}

// ---------------------------------------------------------------------------
// Kernel 2: implicit-GEMM conv (bf16 MFMA) + RFF epilogue with full-L2-line
// channel-monotone write-out.
// grid = (64 oh, 8 b) = 512 blocks; block = 512 thr = 8 waves
// (4 px-quarters x 2 oc-halves). Block tile: 64 px (full oh row) x 32 oc
// x 10 mc. Per mc: MFMA -> phase tile to LDS -> write-out where each
// 16-lane group stores one COMPLETE 256B channel row (2 full L2 lines) per
// instruction, 4 consecutive channels/instr, ascending channel order.
// No output L2 line is ever split across blocks or instructions.
// ---------------------------------------------------------------------------
__global__ __launch_bounds__(512) void conv_rff_mfma(
    const float* __restrict__ x,              // [B][16][128][128]
    const unsigned short* __restrict__ w2,    // [MC][32][160] bf16
    const float* __restrict__ theta,
    float* __restrict__ out)                  // [B][640][64][64]
{
    __shared__ __align__(16) unsigned short Alds[64 * 168];  // im2col, 21.5 KB
    __shared__ __align__(16) float Phase[OUT_C_ * PSTR_];    // 32x68 fl, 8.7 KB

    const int tid = threadIdx.x;
    const int oh  = blockIdx.x;               // 0..63
    const int b   = blockIdx.y;               // 0..7
    const float* __restrict__ xb = x + (size_t)b * (IN_C_ * H_ * W_);

    // ---- im2col: A[px=0..63][k=0..143], then zero-pad k=144..159 ----
#pragma unroll
    for (int j = 0; j < 18; ++j) {            // 18*512 = 9216 = 64*144
        int idx = j * 512 + tid;
        int m = idx & 63;
        int k = idx >> 6;                     // 0..143
        int ic = k & 15;
        int t  = k >> 4;                      // 0..8
        int kh = (t * 11) >> 5;               // t/3
        int kw = t - kh * 3;
        int ih = oh * 2 - 1 + kh;
        int iw = m * 2 - 1 + kw;
        float val = 0.0f;
        if ((unsigned)ih < (unsigned)H_ && (unsigned)iw < (unsigned)W_)
            val = xb[ic * (H_ * W_) + ih * W_ + iw];
        Alds[m * 168 + k] = f2bf(val);
    }
#pragma unroll
    for (int j = 0; j < 2; ++j) {             // 2*512 = 1024 = 64*16 pad
        int idx = j * 512 + tid;
        Alds[(idx & 63) * 168 + 144 + (idx >> 6)] = 0;
    }
    __syncthreads();

    const int lane = tid & 63;
    const int wave = tid >> 6;                // 0..7
    const int h    = wave & 1;                // oc-half: 0/1
    const int q    = wave >> 1;               // px-quarter: 0..3
    const int l15  = lane & 15;
    const int quad = lane >> 4;

    // Pixel (B) fragments: lane holds B[k = quad*8 + j][n = l15] = im2col[px][k]
    short8 pf[5];
#pragma unroll
    for (int ks = 0; ks < 5; ++ks)
        pf[ks] = *(const short8*)&Alds[(q * 16 + l15) * 168 + ks * 32 + quad * 8];

    const float scale = __expf(0.5f * theta[0]) * rsqrtf((float)(OUT_C_ * HW_ * HW_));

    // write-out mapping: thread t -> oc_w = t>>4 (0..31), px0 = (t&15)*4
    const int oc_w = tid >> 4;
    const int px0  = (tid & 15) << 2;
    float* __restrict__ po =
        out + (size_t)b * (MC_ * 2 * OUT_C_ * HW_ * HW_) + oh * HW_ + px0;

    for (int mc = 0; mc < MC_; ++mc) {
        // Weight (A) fragments: lane holds A[m = l15][k = quad*8 + j] = W2[oc][k]
        const unsigned short* __restrict__ wmc = w2 + (size_t)mc * (OUT_C_ * KP_);
        short8 wf[5];
#pragma unroll
        for (int ks = 0; ks < 5; ++ks)
            wf[ks] = *(const short8*)&wmc[(h * 16 + l15) * KP_ + ks * 32 + quad * 8];

        f32x4 acc = {0.f, 0.f, 0.f, 0.f};
#pragma unroll
        for (int ks = 0; ks < 5; ++ks)
            acc = __builtin_amdgcn_mfma_f32_16x16x32_bf16(wf[ks], pf[ks], acc, 0, 0, 0);

        __syncthreads();                      // prev write-out done reading Phase
        // C layout: col = l15 = px (within quarter), row = quad*4 + r = oc
#pragma unroll
        for (int r = 0; r < 4; ++r)
            Phase[(h * 16 + quad * 4 + r) * PSTR_ + q * 16 + l15] = acc[r];
        __syncthreads();

        // write-out: 16 lanes = one full 256B channel row per instruction,
        // 4 consecutive channels per instr, ascending channel order.
        float4 ph = *(const float4*)&Phase[oc_w * PSTR_ + px0];
        float4 cv, sv;
        __sincosf(ph.x, &sv.x, &cv.x);
        __sincosf(ph.y, &sv.y, &cv.y);
        __sincosf(ph.z, &sv.z, &cv.z);
        __sincosf(ph.w, &sv.w, &cv.w);
        cv.x *= scale; cv.y *= scale; cv.z *= scale; cv.w *= scale;
        sv.x *= scale; sv.y *= scale; sv.z *= scale; sv.w *= scale;
        const size_t chc = (size_t)(mc * (2 * OUT_C_) + oc_w) * (HW_ * HW_);
        *(float4*)(po + chc)                              = cv;   // cos plane
        *(float4*)(po + chc + (size_t)OUT_C_ * HW_ * HW_) = sv;   // sin plane
    }
}

// ---------------------------------------------------------------------------
extern "C" void kernel_launch(void* const* d_in, const int* in_sizes, int n_in,
                              void* d_out, int out_size, void* d_ws, size_t ws_size,
                              hipStream_t stream)
{
    const float* x      = (const float*)d_in[0];  // (8,16,128,128)
    const float* theta  = (const float*)d_in[1];  // (1,)
    const float* mean   = (const float*)d_in[2];  // (144,32)
    const float* logsig = (const float*)d_in[3];  // (144,32)
    const float* eps    = (const float*)d_in[4];  // (10,144,32)
    float* out = (float*)d_out;
    unsigned short* W2 = (unsigned short*)d_ws;   // 51200 bf16 = 100 KB

    const int n_w = MC_ * OUT_C_ * KP_;           // 51200
    prep_w_kernel<<<(n_w + 255) / 256, 256, 0, stream>>>(eps, logsig, mean, W2);

    dim3 grid(HW_, B_);                           // (64, 8) = 512 blocks
    conv_rff_mfma<<<grid, 512, 0, stream>>>(x, W2, theta, out);
}